// Round 18
// baseline (76.168 us; speedup 1.0000x reference)
//
#include <hip/hip_runtime.h>
#include <hip/hip_bf16.h>
#include <stdint.h>

typedef __attribute__((ext_vector_type(8))) short short8;
typedef __attribute__((ext_vector_type(4))) short short4v;
typedef __attribute__((ext_vector_type(4))) float f32x4;
typedef __attribute__((ext_vector_type(4))) unsigned uint4v;

#define NB 8
#define NN 2048
#define CC 256
#define LP1 4097
#define HR 192
#define PDim 16
#define KP 224          /* padded K for pair GEMM: 208 real + 16 zero */
#define NPAD 448
#define HEAD_SCALE 0.17677669529663689f  /* 1/sqrt(32) */

#define GLOAD16(g, l) __builtin_amdgcn_global_load_lds( \
    (const __attribute__((address_space(1))) unsigned int*)(g), \
    (__attribute__((address_space(3))) unsigned int*)(l), 16, 0, 0)

static __device__ __forceinline__ unsigned short bf16bits(float f) {
    __hip_bfloat16 h = __float2bfloat16(f);
    return *(unsigned short*)&h;
}

// ---------------- K0: WT + K-pad only ----------------
__global__ __launch_bounds__(256) void k0_prep(
    const float* __restrict__ Wq, const float* __restrict__ Wk,
    const float* __restrict__ Wpi, const float* __restrict__ Wpj,
    const float* __restrict__ Wd,
    __hip_bfloat16* __restrict__ WT,
    unsigned* __restrict__ Ppad, unsigned* __restrict__ Rpad)
{
    const int WTN = NPAD*CC;       // 114688
    const int PV  = NB*NN*2;       // 32768 uint4 items per array
    int i = blockIdx.x*blockDim.x + threadIdx.x;   // grid 704*256 = TOT exactly
    if (i < WTN) {
        int c = i >> 8, k = i & 255;
        float v;
        if (c < HR)                 v = Wq[k*HR + c] * HEAD_SCALE;
        else if (c < 2*HR)          v = Wk[k*HR + (c-HR)];
        else if (c < 2*HR+PDim)     v = Wpi[k*PDim + (c-2*HR)];
        else if (c < 2*HR+2*PDim)   v = Wpj[k*PDim + (c-2*HR-PDim)];
        else if (c == 416)          v = Wd[k];
        else                        v = 0.f;
        WT[i] = __float2bfloat16(v);
    } else {
        int j = i - WTN;
        unsigned* arr = (j < PV) ? Ppad : Rpad;
        int q = (j < PV) ? j : j - PV;
        int row = q >> 1, of = 104 + (q & 1)*4;   // uint cols [104,112)
        *(uint4v*)(arr + (size_t)row*(KP/2) + of) = (uint4v){0,0,0,0};
    }
}

// ---------------- KA: fused fold + projection GEMM, T14 reg-staged B ----
// r12 structure + batch<->XCD affinity (b = hw&7).
__global__ __launch_bounds__(256, 3) void ka_proj(
    const float* __restrict__ feats, const __hip_bfloat16* __restrict__ WT,
    const float* __restrict__ bpi, const float* __restrict__ bpj,
    const float* __restrict__ bd, const float* __restrict__ alpha_pair,
    __hip_bfloat16* __restrict__ P, __hip_bfloat16* __restrict__ R,
    float* __restrict__ dvec)
{
    __shared__ __hip_bfloat16 ldsA[32*256];   // 16 KB A-tile
    __shared__ __hip_bfloat16 ldsB[448*32];   // 28 KB B buffer (single)

    int t = threadIdx.x;
    int lane = t & 63;
    int w = t >> 6;
    int l15 = lane & 15, lg = lane >> 4;
    int hw = blockIdx.x;                     // 512 blocks, 64/batch
    int b = hw & 7;                          // batch <-> XCD affinity
    int n0loc = (hw >> 3) * 32;

    // B: thread t covers rows i*64+(t>>2). key = (row>>2)&3 = (t>>4)&3.
    // source chunk = (t&3) ^ key (pre-swizzled); LDS slot = t&3 (linear).
    int scol = (((t & 3) ^ ((t >> 4) & 3)) << 4);
    const char* srcB[7];
    int wofB[7];
#pragma unroll
    for (int i = 0; i < 7; ++i) {
        int row = i*64 + (t >> 2);
        srcB[i] = (const char*)WT + (size_t)row*512 + scol;
        wofB[i] = row*64 + ((t & 3) << 4);           // LINEAR slot
    }

    // issue B(0) loads first (latency hides under fold)
    uint4v st[7];
#pragma unroll
    for (int i = 0; i < 7; ++i) st[i] = *(const uint4v*)(srcB[i]);

    // ---- fold 64 feats rows -> 32 bf16 rows in LDS A ----
    {
        int r = t >> 3, cg = t & 7;
        size_t fb = ((size_t)b*LP1 + 1 + 2*(size_t)(n0loc + r))*CC + cg*32;
#pragma unroll
        for (int s = 0; s < 4; ++s) {
            float4 a0 = *(const float4*)(feats + fb + s*8);
            float4 a1 = *(const float4*)(feats + fb + s*8 + 4);
            float4 c0 = *(const float4*)(feats + fb + CC + s*8);
            float4 c1 = *(const float4*)(feats + fb + CC + s*8 + 4);
            unsigned short h[8];
            h[0] = bf16bits(0.5f*(a0.x + c0.x));
            h[1] = bf16bits(0.5f*(a0.y + c0.y));
            h[2] = bf16bits(0.5f*(a0.z + c0.z));
            h[3] = bf16bits(0.5f*(a0.w + c0.w));
            h[4] = bf16bits(0.5f*(a1.x + c1.x));
            h[5] = bf16bits(0.5f*(a1.y + c1.y));
            h[6] = bf16bits(0.5f*(a1.z + c1.z));
            h[7] = bf16bits(0.5f*(a1.w + c1.w));
            int slot = (cg*4 + s) ^ (r & 7);
            *(short8*)((char*)ldsA + r*512 + slot*16) = *(const short8*)h;
        }
    }

    // write B(0) to LDS
#pragma unroll
    for (int i = 0; i < 7; ++i)
        *(uint4v*)((char*)ldsB + wofB[i]) = st[i];
    __syncthreads();

    // ---- pipelined GEMM ----
    f32x4 acc[7][2];   // [ni][mi]
#pragma unroll
    for (int ni = 0; ni < 7; ++ni)
#pragma unroll
        for (int mi = 0; mi < 2; ++mi)
            acc[ni][mi] = (f32x4){0.f, 0.f, 0.f, 0.f};

    int arow[2];
#pragma unroll
    for (int mi = 0; mi < 2; ++mi) arow[mi] = (mi*16 + l15)*512;
    int rx = l15 & 7;
    // B read: row = w*112+ni*16+l15, key = (row>>2)&3 = (l15>>2)&3
    int bbase = (w*112 + l15)*64 + ((lg ^ ((l15 >> 2) & 3)) << 4);

#pragma unroll
    for (int kk = 0; kk < 8; ++kk) {
        // T14: issue next B-step loads BEFORE compute
        if (kk < 7) {
#pragma unroll
            for (int i = 0; i < 7; ++i)
                st[i] = *(const uint4v*)(srcB[i] + (size_t)(kk + 1)*64);
        }
        short8 a[2], bb[7];
        int slotb = ((kk*4 + lg) ^ rx) << 4;
#pragma unroll
        for (int mi = 0; mi < 2; ++mi)
            a[mi] = *(const short8*)((const char*)ldsA + arow[mi] + slotb);
#pragma unroll
        for (int ni = 0; ni < 7; ++ni)
            bb[ni] = *(const short8*)((const char*)ldsB + bbase + ni*1024);
#pragma unroll
        for (int ni = 0; ni < 7; ++ni)
#pragma unroll
            for (int mi = 0; mi < 2; ++mi)
                acc[ni][mi] = __builtin_amdgcn_mfma_f32_16x16x32_bf16(
                    bb[ni], a[mi], acc[ni][mi], 0, 0, 0);

        __syncthreads();   // all waves done reading ldsB(kk)
        if (kk < 7) {
#pragma unroll
            for (int i = 0; i < 7; ++i)
                *(uint4v*)((char*)ldsB + wofB[i]) = st[i];
            __syncthreads();   // B(kk+1) visible
        }
    }

    // ---- routed epilogue ----
    float alpha_eff = fmaxf(alpha_pair[0], 0.f);
    float bd0 = bd[0];
#pragma unroll
    for (int ni = 0; ni < 7; ++ni) {
        int cb = w*112 + ni*16 + lg*4;
#pragma unroll
        for (int mi = 0; mi < 2; ++mi) {
            int n = n0loc + mi*16 + l15;
            size_t rb = ((size_t)b*NN + n)*KP;
            f32x4 v = acc[ni][mi];
            if (cb < HR) {
                short4v h;
#pragma unroll
                for (int j = 0; j < 4; ++j) h[j] = (short)bf16bits(v[j]);
                *(short4v*)(P + rb + cb) = h;                    // Q*scale
            } else if (cb < 2*HR) {
                short4v h;
#pragma unroll
                for (int j = 0; j < 4; ++j) h[j] = (short)bf16bits(v[j]);
                *(short4v*)(R + rb + (cb - HR)) = h;             // K
            } else if (cb < 2*HR + PDim) {
                int pc = cb - 2*HR;
                short4v h;
#pragma unroll
                for (int j = 0; j < 4; ++j)
                    h[j] = (short)bf16bits(fmaxf(v[j] + bpi[pc+j], 0.f) * alpha_eff);
                *(short4v*)(P + rb + HR + pc) = h;               // alpha*a_i
            } else if (cb < 2*HR + 2*PDim) {
                int pc = cb - 2*HR - PDim;
                short4v h;
#pragma unroll
                for (int j = 0; j < 4; ++j)
                    h[j] = (short)bf16bits(fmaxf(v[j] + bpj[pc+j], 0.f));
                *(short4v*)(R + rb + HR + pc) = h;               // b_j
            } else if (cb == 416) {
                dvec[(size_t)b*NN + n] = v[0] + bd0;             // d
            }
        }
    }
}

// ---------------- KB: batched pair GEMM, 2-tile continuous pipeline -------
// Each block: TWO 128^2 tiles (same n0, m0base and m0base+128). Unified
// 14-step schedule, staging runs continuously across the tile boundary:
// step s stages step s+2, vmcnt(4) for s<13, single vmcnt(0) at s=13.
// Tile-0's epilogue stores overlap tile-1's in-flight staging -> one
// exposed prologue + one drain per PAIR instead of per tile.
__global__ __launch_bounds__(256, 4) void kb_pair(
    const __hip_bfloat16* __restrict__ P, const __hip_bfloat16* __restrict__ R,
    const float* __restrict__ dvec, const float* __restrict__ logit_scale,
    float* __restrict__ out)
{
    __shared__ __hip_bfloat16 ldsA[2][128*32];
    __shared__ __hip_bfloat16 ldsB[2][128*32];

    int t = threadIdx.x;
    int lane = t & 63;
    int w = t >> 6;
    int wr = w >> 1, wc = w & 1;
    int l15 = lane & 15, lg = lane >> 4;

    int hw = blockIdx.x;            // 0..1023
    int b = hw & 7;                 // batch <-> XCD affinity
    int p = hw >> 3;                // 0..127 tile-pair index
    int n0 = (p >> 3) << 7;         // 16 row strips (P rows)
    int m0base = (p & 7) << 8;      // 8 col pairs; tile m0 = m0base + tile*128
    const size_t TOFF = 128 * KP * 2;   // 57344 B: tile-1 B-row offset

    // staging sources, pre-swizzled with key = (row>>2)&3 = (t>>4)&3
    const char* srcA[2];
    const char* srcB[2];
    {
        int scolb = (((t & 3) ^ ((t >> 4) & 3)) << 4);
#pragma unroll
        for (int i = 0; i < 2; ++i) {
            int row = i*64 + (t >> 2);
            srcA[i] = (const char*)(P + ((size_t)b*NN + n0 + row)*KP) + scolb;
            srcB[i] = (const char*)(R + ((size_t)b*NN + m0base + row)*KP) + scolb;
        }
    }
    int ldst = w * 1024;   // wave-uniform LDS dest base (+ lane*16 by HW)

    // ds_read: key = (row>>2)&3 = (l15>>2)&3
    int abyte = (wr*64 + l15)*64 + ((lg ^ ((l15 >> 2) & 3)) << 4);
    int bbyte = (wc*64 + l15)*64 + ((lg ^ ((l15 >> 2) & 3)) << 4);

    float ls = fmaxf(logit_scale[0], 0.01f);

    f32x4 acc[4][4];   // [ni][mi]
#pragma unroll
    for (int ni = 0; ni < 4; ++ni)
#pragma unroll
        for (int mi = 0; mi < 4; ++mi)
            acc[ni][mi] = (f32x4){0.f, 0.f, 0.f, 0.f};

    // stage helper: step 0..13; K-chunk = step%7, tile = step>=7, buf = step&1
    auto STAGE = [&](int step) {
        size_t kof = (size_t)(step % 7) * 64;
        size_t bof = (step >= 7) ? TOFF : 0;
        int buf = step & 1;
        GLOAD16(srcA[0] + kof,       (char*)(&ldsA[buf][0]) + 0*4096 + ldst);
        GLOAD16(srcB[0] + bof + kof, (char*)(&ldsB[buf][0]) + 0*4096 + ldst);
        GLOAD16(srcA[1] + kof,       (char*)(&ldsA[buf][0]) + 1*4096 + ldst);
        GLOAD16(srcB[1] + bof + kof, (char*)(&ldsB[buf][0]) + 1*4096 + ldst);
    };

    auto COMPUTE = [&](int s) {
        const int buf = s & 1;
        short8 a[4], bb[4];
#pragma unroll
        for (int mi = 0; mi < 4; ++mi)
            a[mi] = *(const short8*)((const char*)(&ldsA[buf][0]) + abyte + mi*1024);
#pragma unroll
        for (int ni = 0; ni < 4; ++ni)
            bb[ni] = *(const short8*)((const char*)(&ldsB[buf][0]) + bbyte + ni*1024);
#pragma unroll
        for (int ni = 0; ni < 4; ++ni)
#pragma unroll
            for (int mi = 0; mi < 4; ++mi)
                acc[ni][mi] = __builtin_amdgcn_mfma_f32_16x16x32_bf16(
                    bb[ni], a[mi], acc[ni][mi], 0, 0, 0);
    };

    auto EPILOGUE = [&](int m0t) {
        bool diag_tile = (n0 == m0t);
#pragma unroll
        for (int mi = 0; mi < 4; ++mi) {
            int orow = n0 + wr*64 + mi*16 + l15;             // D col -> out row
            float* orow_p = out + ((size_t)b*NN + orow)*NN;
            float dval = diag_tile ? dvec[(size_t)b*NN + orow] : 0.f;
#pragma unroll
            for (int ni = 0; ni < 4; ++ni) {
                int cbase = m0t + wc*64 + ni*16 + lg*4;      // D rows -> cols
                f32x4 v = acc[ni][mi];
                if (diag_tile) {
                    int dj = orow - cbase;
                    if (dj >= 0 && dj < 4) v[dj] += dval;
                }
                f32x4 o;
#pragma unroll
                for (int j = 0; j < 4; ++j) o[j] = v[j] * ls;
                *(f32x4*)(orow_p + cbase) = o;
            }
        }
    };

    // prologue: stage steps 0,1
    STAGE(0);
    STAGE(1);

    // ---- tile 0: steps 0..6 ----
#pragma unroll
    for (int s = 0; s < 7; ++s) {
        asm volatile("s_waitcnt vmcnt(4)" ::: "memory");
        __builtin_amdgcn_s_barrier();
        __builtin_amdgcn_sched_barrier(0);
        COMPUTE(s);
        __builtin_amdgcn_sched_barrier(0);
        __builtin_amdgcn_s_barrier();   // all waves done reading buf
        STAGE(s + 2);                   // steps 2..8 (crosses into tile 1)
    }

    EPILOGUE(m0base);                   // tile-1 staging in flight underneath
#pragma unroll
    for (int ni = 0; ni < 4; ++ni)
#pragma unroll
        for (int mi = 0; mi < 4; ++mi)
            acc[ni][mi] = (f32x4){0.f, 0.f, 0.f, 0.f};

    // ---- tile 1: steps 7..13 ----
#pragma unroll
    for (int s = 7; s < 14; ++s) {
        if (s < 13) asm volatile("s_waitcnt vmcnt(4)" ::: "memory");
        else        asm volatile("s_waitcnt vmcnt(0)" ::: "memory");
        __builtin_amdgcn_s_barrier();
        __builtin_amdgcn_sched_barrier(0);
        COMPUTE(s);
        __builtin_amdgcn_sched_barrier(0);
        __builtin_amdgcn_s_barrier();
        if (s + 2 < 14) STAGE(s + 2);   // steps 9..13
    }

    EPILOGUE(m0base + 128);
}

extern "C" void kernel_launch(void* const* d_in, const int* in_sizes, int n_in,
                              void* d_out, int out_size, void* d_ws, size_t ws_size,
                              hipStream_t stream)
{
    const float* feats = (const float*)d_in[0];
    const float* Wq    = (const float*)d_in[1];
    const float* Wk    = (const float*)d_in[2];
    const float* Wpi   = (const float*)d_in[3];
    const float* bpi   = (const float*)d_in[4];
    const float* Wpj   = (const float*)d_in[5];
    const float* bpj   = (const float*)d_in[6];
    const float* Wd    = (const float*)d_in[7];
    const float* bd    = (const float*)d_in[8];
    const float* alpha = (const float*)d_in[9];
    const float* lsc   = (const float*)d_in[10];

    char* ws = (char*)d_ws;
    __hip_bfloat16* WT = (__hip_bfloat16*)(ws);               //   229,376 B
    __hip_bfloat16* P  = (__hip_bfloat16*)(ws + 229376);      // 7,340,032 B
    __hip_bfloat16* R  = (__hip_bfloat16*)(ws + 7569408);     // 7,340,032 B
    float*          dv = (float*)(ws + 14909440);             //    65,536 B

    k0_prep<<<704, 256, 0, stream>>>(Wq, Wk, Wpi, Wpj, Wd,
                                     WT, (unsigned*)P, (unsigned*)R);
    ka_proj<<<512, 256, 0, stream>>>(feats, WT, bpi, bpj, bd, alpha, P, R, dv);
    kb_pair<<<1024, 256, 0, stream>>>(P, R, dv, lsc, (float*)d_out);
}

// Round 19
// 63.942 us; speedup vs baseline: 1.1912x; 1.1912x over previous
//
#include <hip/hip_runtime.h>
#include <hip/hip_bf16.h>
#include <stdint.h>

typedef __attribute__((ext_vector_type(8))) short short8;
typedef __attribute__((ext_vector_type(4))) short short4v;
typedef __attribute__((ext_vector_type(4))) float f32x4;
typedef __attribute__((ext_vector_type(4))) unsigned uint4v;

#define NB 8
#define NN 2048
#define CC 256
#define LP1 4097
#define HR 192
#define PDim 16
#define KP 224          /* padded K for pair GEMM: 208 real + 16 zero */
#define NPAD 448
#define HEAD_SCALE 0.17677669529663689f  /* 1/sqrt(32) */

#define GLOAD16(g, l) __builtin_amdgcn_global_load_lds( \
    (const __attribute__((address_space(1))) unsigned int*)(g), \
    (__attribute__((address_space(3))) unsigned int*)(l), 16, 0, 0)

static __device__ __forceinline__ unsigned short bf16bits(float f) {
    __hip_bfloat16 h = __float2bfloat16(f);
    return *(unsigned short*)&h;
}

// ---------------- K0: WT + K-pad only ----------------
__global__ __launch_bounds__(256) void k0_prep(
    const float* __restrict__ Wq, const float* __restrict__ Wk,
    const float* __restrict__ Wpi, const float* __restrict__ Wpj,
    const float* __restrict__ Wd,
    __hip_bfloat16* __restrict__ WT,
    unsigned* __restrict__ Ppad, unsigned* __restrict__ Rpad)
{
    const int WTN = NPAD*CC;       // 114688
    const int PV  = NB*NN*2;       // 32768 uint4 items per array
    int i = blockIdx.x*blockDim.x + threadIdx.x;   // grid 704*256 = TOT exactly
    if (i < WTN) {
        int c = i >> 8, k = i & 255;
        float v;
        if (c < HR)                 v = Wq[k*HR + c] * HEAD_SCALE;
        else if (c < 2*HR)          v = Wk[k*HR + (c-HR)];
        else if (c < 2*HR+PDim)     v = Wpi[k*PDim + (c-2*HR)];
        else if (c < 2*HR+2*PDim)   v = Wpj[k*PDim + (c-2*HR-PDim)];
        else if (c == 416)          v = Wd[k];
        else                        v = 0.f;
        WT[i] = __float2bfloat16(v);
    } else {
        int j = i - WTN;
        unsigned* arr = (j < PV) ? Ppad : Rpad;
        int q = (j < PV) ? j : j - PV;
        int row = q >> 1, of = 104 + (q & 1)*4;   // uint cols [104,112)
        *(uint4v*)(arr + (size_t)row*(KP/2) + of) = (uint4v){0,0,0,0};
    }
}

// ---------------- KA: fused fold + projection GEMM, T14 reg-staged B ----
// r12 structure + batch<->XCD affinity (b = hw&7).
__global__ __launch_bounds__(256, 3) void ka_proj(
    const float* __restrict__ feats, const __hip_bfloat16* __restrict__ WT,
    const float* __restrict__ bpi, const float* __restrict__ bpj,
    const float* __restrict__ bd, const float* __restrict__ alpha_pair,
    __hip_bfloat16* __restrict__ P, __hip_bfloat16* __restrict__ R,
    float* __restrict__ dvec)
{
    __shared__ __hip_bfloat16 ldsA[32*256];   // 16 KB A-tile
    __shared__ __hip_bfloat16 ldsB[448*32];   // 28 KB B buffer (single)

    int t = threadIdx.x;
    int lane = t & 63;
    int w = t >> 6;
    int l15 = lane & 15, lg = lane >> 4;
    int hw = blockIdx.x;                     // 512 blocks, 64/batch
    int b = hw & 7;                          // batch <-> XCD affinity
    int n0loc = (hw >> 3) * 32;

    // B: thread t covers rows i*64+(t>>2). key = (row>>2)&3 = (t>>4)&3.
    // source chunk = (t&3) ^ key (pre-swizzled); LDS slot = t&3 (linear).
    int scol = (((t & 3) ^ ((t >> 4) & 3)) << 4);
    const char* srcB[7];
    int wofB[7];
#pragma unroll
    for (int i = 0; i < 7; ++i) {
        int row = i*64 + (t >> 2);
        srcB[i] = (const char*)WT + (size_t)row*512 + scol;
        wofB[i] = row*64 + ((t & 3) << 4);           // LINEAR slot
    }

    // issue B(0) loads first (latency hides under fold)
    uint4v st[7];
#pragma unroll
    for (int i = 0; i < 7; ++i) st[i] = *(const uint4v*)(srcB[i]);

    // ---- fold 64 feats rows -> 32 bf16 rows in LDS A ----
    {
        int r = t >> 3, cg = t & 7;
        size_t fb = ((size_t)b*LP1 + 1 + 2*(size_t)(n0loc + r))*CC + cg*32;
#pragma unroll
        for (int s = 0; s < 4; ++s) {
            float4 a0 = *(const float4*)(feats + fb + s*8);
            float4 a1 = *(const float4*)(feats + fb + s*8 + 4);
            float4 c0 = *(const float4*)(feats + fb + CC + s*8);
            float4 c1 = *(const float4*)(feats + fb + CC + s*8 + 4);
            unsigned short h[8];
            h[0] = bf16bits(0.5f*(a0.x + c0.x));
            h[1] = bf16bits(0.5f*(a0.y + c0.y));
            h[2] = bf16bits(0.5f*(a0.z + c0.z));
            h[3] = bf16bits(0.5f*(a0.w + c0.w));
            h[4] = bf16bits(0.5f*(a1.x + c1.x));
            h[5] = bf16bits(0.5f*(a1.y + c1.y));
            h[6] = bf16bits(0.5f*(a1.z + c1.z));
            h[7] = bf16bits(0.5f*(a1.w + c1.w));
            int slot = (cg*4 + s) ^ (r & 7);
            *(short8*)((char*)ldsA + r*512 + slot*16) = *(const short8*)h;
        }
    }

    // write B(0) to LDS
#pragma unroll
    for (int i = 0; i < 7; ++i)
        *(uint4v*)((char*)ldsB + wofB[i]) = st[i];
    __syncthreads();

    // ---- pipelined GEMM ----
    f32x4 acc[7][2];   // [ni][mi]
#pragma unroll
    for (int ni = 0; ni < 7; ++ni)
#pragma unroll
        for (int mi = 0; mi < 2; ++mi)
            acc[ni][mi] = (f32x4){0.f, 0.f, 0.f, 0.f};

    int arow[2];
#pragma unroll
    for (int mi = 0; mi < 2; ++mi) arow[mi] = (mi*16 + l15)*512;
    int rx = l15 & 7;
    // B read: row = w*112+ni*16+l15, key = (row>>2)&3 = (l15>>2)&3
    int bbase = (w*112 + l15)*64 + ((lg ^ ((l15 >> 2) & 3)) << 4);

#pragma unroll
    for (int kk = 0; kk < 8; ++kk) {
        // T14: issue next B-step loads BEFORE compute
        if (kk < 7) {
#pragma unroll
            for (int i = 0; i < 7; ++i)
                st[i] = *(const uint4v*)(srcB[i] + (size_t)(kk + 1)*64);
        }
        short8 a[2], bb[7];
        int slotb = ((kk*4 + lg) ^ rx) << 4;
#pragma unroll
        for (int mi = 0; mi < 2; ++mi)
            a[mi] = *(const short8*)((const char*)ldsA + arow[mi] + slotb);
#pragma unroll
        for (int ni = 0; ni < 7; ++ni)
            bb[ni] = *(const short8*)((const char*)ldsB + bbase + ni*1024);
#pragma unroll
        for (int ni = 0; ni < 7; ++ni)
#pragma unroll
            for (int mi = 0; mi < 2; ++mi)
                acc[ni][mi] = __builtin_amdgcn_mfma_f32_16x16x32_bf16(
                    bb[ni], a[mi], acc[ni][mi], 0, 0, 0);

        __syncthreads();   // all waves done reading ldsB(kk)
        if (kk < 7) {
#pragma unroll
            for (int i = 0; i < 7; ++i)
                *(uint4v*)((char*)ldsB + wofB[i]) = st[i];
            __syncthreads();   // B(kk+1) visible
        }
    }

    // ---- routed epilogue ----
    float alpha_eff = fmaxf(alpha_pair[0], 0.f);
    float bd0 = bd[0];
#pragma unroll
    for (int ni = 0; ni < 7; ++ni) {
        int cb = w*112 + ni*16 + lg*4;
#pragma unroll
        for (int mi = 0; mi < 2; ++mi) {
            int n = n0loc + mi*16 + l15;
            size_t rb = ((size_t)b*NN + n)*KP;
            f32x4 v = acc[ni][mi];
            if (cb < HR) {
                short4v h;
#pragma unroll
                for (int j = 0; j < 4; ++j) h[j] = (short)bf16bits(v[j]);
                *(short4v*)(P + rb + cb) = h;                    // Q*scale
            } else if (cb < 2*HR) {
                short4v h;
#pragma unroll
                for (int j = 0; j < 4; ++j) h[j] = (short)bf16bits(v[j]);
                *(short4v*)(R + rb + (cb - HR)) = h;             // K
            } else if (cb < 2*HR + PDim) {
                int pc = cb - 2*HR;
                short4v h;
#pragma unroll
                for (int j = 0; j < 4; ++j)
                    h[j] = (short)bf16bits(fmaxf(v[j] + bpi[pc+j], 0.f) * alpha_eff);
                *(short4v*)(P + rb + HR + pc) = h;               // alpha*a_i
            } else if (cb < 2*HR + 2*PDim) {
                int pc = cb - 2*HR - PDim;
                short4v h;
#pragma unroll
                for (int j = 0; j < 4; ++j)
                    h[j] = (short)bf16bits(fmaxf(v[j] + bpj[pc+j], 0.f));
                *(short4v*)(R + rb + HR + pc) = h;               // b_j
            } else if (cb == 416) {
                dvec[(size_t)b*NN + n] = v[0] + bd0;             // d
            }
        }
    }
}

// ---------------- KB: batched pair GEMM (r16 best: r12 2-deep, balanced
// swizzle, mi-outer epilogue, plain cached stores) -------------------------
__global__ __launch_bounds__(256, 4) void kb_pair(
    const __hip_bfloat16* __restrict__ P, const __hip_bfloat16* __restrict__ R,
    const float* __restrict__ dvec, const float* __restrict__ logit_scale,
    float* __restrict__ out)
{
    __shared__ __hip_bfloat16 ldsA[2][128*32];
    __shared__ __hip_bfloat16 ldsB[2][128*32];

    int t = threadIdx.x;
    int lane = t & 63;
    int w = t >> 6;
    int wr = w >> 1, wc = w & 1;
    int l15 = lane & 15, lg = lane >> 4;

    int hw = blockIdx.x;
    int b = hw & 7;                 // batch <-> XCD affinity
    int within = hw >> 3;           // 0..255
    int m0 = (within & 15) << 7;    // output cols (R rows)
    int n0 = (within >> 4) << 7;    // output rows (P rows)

    // staging sources, pre-swizzled with key = (row>>2)&3 = (t>>4)&3
    const char* srcA[2];
    const char* srcB[2];
    {
        int scolb = (((t & 3) ^ ((t >> 4) & 3)) << 4);
#pragma unroll
        for (int i = 0; i < 2; ++i) {
            int row = i*64 + (t >> 2);
            srcA[i] = (const char*)(P + ((size_t)b*NN + n0 + row)*KP) + scolb;
            srcB[i] = (const char*)(R + ((size_t)b*NN + m0 + row)*KP) + scolb;
        }
    }
    int ldst = w * 1024;   // wave-uniform LDS dest base (+ lane*16 by HW)

    // ds_read: key = (row>>2)&3 = (l15>>2)&3
    int abyte = (wr*64 + l15)*64 + ((lg ^ ((l15 >> 2) & 3)) << 4);
    int bbyte = (wc*64 + l15)*64 + ((lg ^ ((l15 >> 2) & 3)) << 4);

    f32x4 acc[4][4];   // [ni][mi]
#pragma unroll
    for (int ni = 0; ni < 4; ++ni)
#pragma unroll
        for (int mi = 0; mi < 4; ++mi)
            acc[ni][mi] = (f32x4){0.f, 0.f, 0.f, 0.f};

    // prologue: stage step 0 -> buf0, step 1 -> buf1 (8 loads in flight)
#pragma unroll
    for (int i = 0; i < 2; ++i) {
        GLOAD16(srcA[i], (char*)(&ldsA[0][0]) + i*4096 + ldst);
        GLOAD16(srcB[i], (char*)(&ldsB[0][0]) + i*4096 + ldst);
    }
#pragma unroll
    for (int i = 0; i < 2; ++i) {
        GLOAD16(srcA[i] + 64, (char*)(&ldsA[1][0]) + i*4096 + ldst);
        GLOAD16(srcB[i] + 64, (char*)(&ldsB[1][0]) + i*4096 + ldst);
    }

#pragma unroll
    for (int s = 0; s < 7; ++s) {   // 7 K-steps of 32 (KP=224)
        if (s < 6) asm volatile("s_waitcnt vmcnt(4)" ::: "memory");
        else       asm volatile("s_waitcnt vmcnt(0)" ::: "memory");
        __builtin_amdgcn_s_barrier();
        __builtin_amdgcn_sched_barrier(0);

        const int buf = s & 1;
        short8 a[4], bb[4];
#pragma unroll
        for (int mi = 0; mi < 4; ++mi)
            a[mi] = *(const short8*)((const char*)(&ldsA[buf][0]) + abyte + mi*1024);
#pragma unroll
        for (int ni = 0; ni < 4; ++ni)
            bb[ni] = *(const short8*)((const char*)(&ldsB[buf][0]) + bbyte + ni*1024);
#pragma unroll
        for (int ni = 0; ni < 4; ++ni)
#pragma unroll
            for (int mi = 0; mi < 4; ++mi)
                acc[ni][mi] = __builtin_amdgcn_mfma_f32_16x16x32_bf16(
                    bb[ni], a[mi], acc[ni][mi], 0, 0, 0);

        __builtin_amdgcn_sched_barrier(0);
        __builtin_amdgcn_s_barrier();   // all waves done reading buf
        if (s + 2 < 7) {
            size_t kof = (size_t)(s + 2) * 64;
#pragma unroll
            for (int i = 0; i < 2; ++i) {
                GLOAD16(srcA[i] + kof, (char*)(&ldsA[buf][0]) + i*4096 + ldst);
                GLOAD16(srcB[i] + kof, (char*)(&ldsB[buf][0]) + i*4096 + ldst);
            }
        }
    }

    float ls = fmaxf(logit_scale[0], 0.01f);
    bool diag_tile = (n0 == m0);
    // mi OUTER / ni INNER: per row, 4 consecutive stores cover cols
    // [wc*64, wc*64+64) = two full 128-B lines, adjacent in program order.
#pragma unroll
    for (int mi = 0; mi < 4; ++mi) {
        int orow = n0 + wr*64 + mi*16 + l15;                 // D col -> out row
        float* orow_p = out + ((size_t)b*NN + orow)*NN;
        float dval = diag_tile ? dvec[(size_t)b*NN + orow] : 0.f;
#pragma unroll
        for (int ni = 0; ni < 4; ++ni) {
            int cbase = m0 + wc*64 + ni*16 + lg*4;           // D rows -> out cols
            f32x4 v = acc[ni][mi];
            if (diag_tile) {
                int dj = orow - cbase;
                if (dj >= 0 && dj < 4) v[dj] += dval;
            }
            f32x4 o;
#pragma unroll
            for (int j = 0; j < 4; ++j) o[j] = v[j] * ls;
            *(f32x4*)(orow_p + cbase) = o;
        }
    }
}

extern "C" void kernel_launch(void* const* d_in, const int* in_sizes, int n_in,
                              void* d_out, int out_size, void* d_ws, size_t ws_size,
                              hipStream_t stream)
{
    const float* feats = (const float*)d_in[0];
    const float* Wq    = (const float*)d_in[1];
    const float* Wk    = (const float*)d_in[2];
    const float* Wpi   = (const float*)d_in[3];
    const float* bpi   = (const float*)d_in[4];
    const float* Wpj   = (const float*)d_in[5];
    const float* bpj   = (const float*)d_in[6];
    const float* Wd    = (const float*)d_in[7];
    const float* bd    = (const float*)d_in[8];
    const float* alpha = (const float*)d_in[9];
    const float* lsc   = (const float*)d_in[10];

    char* ws = (char*)d_ws;
    __hip_bfloat16* WT = (__hip_bfloat16*)(ws);               //   229,376 B
    __hip_bfloat16* P  = (__hip_bfloat16*)(ws + 229376);      // 7,340,032 B
    __hip_bfloat16* R  = (__hip_bfloat16*)(ws + 7569408);     // 7,340,032 B
    float*          dv = (float*)(ws + 14909440);             //    65,536 B

    k0_prep<<<704, 256, 0, stream>>>(Wq, Wk, Wpi, Wpj, Wd,
                                     WT, (unsigned*)P, (unsigned*)R);
    ka_proj<<<512, 256, 0, stream>>>(feats, WT, bpi, bpj, bd, alpha, P, R, dv);
    kb_pair<<<2048, 256, 0, stream>>>(P, R, dv, lsc, (float*)d_out);
}